// Round 4
// baseline (5671.817 us; speedup 1.0000x reference)
//
#include <hip/hip_runtime.h>
#include <hip/hip_bf16.h>
#include <math.h>

typedef __attribute__((ext_vector_type(8))) short bf16x8;
typedef __attribute__((ext_vector_type(4))) float f32x4;
typedef __attribute__((ext_vector_type(4))) int i32x4;
typedef __attribute__((ext_vector_type(2))) int i32x2;
typedef __attribute__((ext_vector_type(2))) unsigned int u32x2;

#define TT 1024
#define BB 128
#define II 256
#define SS 512
#define OUT_T 1025
#define OUT_BSTRIDE ((size_t)OUT_T * SS)   // 524800

// ---------- bf16 helpers ----------
static __device__ __forceinline__ unsigned short f2bf(float f) {
  union { float f; unsigned int u; } v; v.f = f;
  unsigned int r = v.u + 0x7fffu + ((v.u >> 16) & 1u);
  return (unsigned short)(r >> 16);
}
static __device__ __forceinline__ float bf2f(unsigned short h) {
  union { unsigned int u; float f; } v; v.u = ((unsigned int)h) << 16;
  return v.f;
}
static __device__ __forceinline__ bf16x8 pack8(const float* p) {
  float4 a = *(const float4*)p;
  float4 b = *(const float4*)(p + 4);
  bf16x8 r;
  r[0]=(short)f2bf(a.x); r[1]=(short)f2bf(a.y); r[2]=(short)f2bf(a.z); r[3]=(short)f2bf(a.w);
  r[4]=(short)f2bf(b.x); r[5]=(short)f2bf(b.y); r[6]=(short)f2bf(b.z); r[7]=(short)f2bf(b.w);
  return r;
}
static __device__ __forceinline__ float bfat(u32x2 v, int q) {
  unsigned int u = (q < 2) ? v[0] : v[1];
  u = (q & 1) ? (u >> 16) : (u & 0xffffu);
  return bf2f((unsigned short)u);
}
// tanh via exp2; clamp avoids inf/inf
static __device__ __forceinline__ float fast_tanh(float x) {
  float x2 = fminf(x * 2.8853900817779268f, 88.0f);
  float e = __builtin_amdgcn_exp2f(x2);
  return (e - 1.0f) * __builtin_amdgcn_rcpf(e + 1.0f);
}

// ---------- device-coherent (cross-XCD safe, LLC) ops ----------
static __device__ __forceinline__ i32x4 ld_coh_b128_issue(const void* p) {
  i32x4 r;
  asm volatile("global_load_dwordx4 %0, %1, off sc0 sc1" : "=v"(r) : "v"(p) : "memory");
  return r;
}
static __device__ __forceinline__ unsigned int ld_coh_b32(const void* p) {
  unsigned int r;
  asm volatile("global_load_dword %0, %1, off sc0 sc1\n\ts_waitcnt vmcnt(0)"
               : "=v"(r) : "v"(p) : "memory");
  return r;
}
static __device__ __forceinline__ void st_coh_b64(void* p, i32x2 v) {
  asm volatile("global_store_dwordx2 %0, %1, off sc0 sc1" :: "v"(p), "v"(v) : "memory");
}
static __device__ __forceinline__ void st_coh_b32(void* p, unsigned int v) {
  asm volatile("global_store_dword %0, %1, off sc0 sc1" :: "v"(p), "v"(v) : "memory");
}
static __device__ __forceinline__ void waitcnt_vm0() {
  asm volatile("s_waitcnt vmcnt(0)" ::: "memory");
}

// =====================================================================
// Phase 1: projections. Grid = 2048 m-blocks (64 rows each); x staged ONCE
// in LDS per block; inner loop over all 24 n-tiles (x HBM-read exactly once).
// proj[t][b][1536] bf16: [0:512)=x@B0w^T+b0, [512:1024)=x@B1w^T+b1,
// [1024:1536)=sigmoid(x@Gw^T+gb).
// =====================================================================
__global__ __launch_bounds__(256) void proj_kernel(
    const float* __restrict__ x,
    const float* __restrict__ B0w, const float* __restrict__ B0b,
    const float* __restrict__ B1w, const float* __restrict__ B1b,
    const float* __restrict__ Gw,  const float* __restrict__ Gb,
    unsigned short* __restrict__ proj)
{
  __shared__ unsigned short Xs[64 * 264];   // 33,792 B (x tile, resident)
  __shared__ unsigned short Ws[64 * 40];    // 5,120 B (W k-chunk)

  int m0 = blockIdx.x * 64;
  int tid = threadIdx.x, lane = tid & 63, wid = tid >> 6;
  int lane15 = lane & 15, kslot = lane >> 4;
  int mt0 = (wid >> 1) * 2, nt0 = (wid & 1) * 2;
  int sr = tid >> 2, sc = tid & 3;

#pragma unroll
  for (int it = 0; it < 8; ++it) {
    int task = tid + 256 * it; int r = task >> 5, c = task & 31;
    *(bf16x8*)&Xs[r * 264 + c * 8] = pack8(x + (size_t)(m0 + r) * II + c * 8);
  }
  __syncthreads();

  for (int nt = 0; nt < 24; ++nt) {
    int n0 = nt * 64;
    const float* Wp; const float* bp; bool isgate = false;
    if (n0 < 512)       { Wp = B0w + (size_t)n0 * II;          bp = B0b + n0; }
    else if (n0 < 1024) { Wp = B1w + (size_t)(n0 - 512) * II;  bp = B1b + (n0 - 512); }
    else                { Wp = Gw  + (size_t)(n0 - 1024) * II; bp = Gb + (n0 - 1024); isgate = true; }

    f32x4 acc[2][2] = {};
    for (int k0 = 0; k0 < II; k0 += 32) {
      __syncthreads();   // prev chunk reads done
      *(bf16x8*)&Ws[sr * 40 + sc * 8] = pack8(Wp + (size_t)sr * II + k0 + sc * 8);
      __syncthreads();
      bf16x8 af[2], bf[2];
#pragma unroll
      for (int mi = 0; mi < 2; ++mi)
        af[mi] = *(const bf16x8*)&Xs[((mt0 + mi) * 16 + lane15) * 264 + k0 + 8 * kslot];
#pragma unroll
      for (int ni = 0; ni < 2; ++ni)
        bf[ni] = *(const bf16x8*)&Ws[((nt0 + ni) * 16 + lane15) * 40 + 8 * kslot];
#pragma unroll
      for (int mi = 0; mi < 2; ++mi)
#pragma unroll
        for (int ni = 0; ni < 2; ++ni)
          acc[mi][ni] = __builtin_amdgcn_mfma_f32_16x16x32_bf16(af[mi], bf[ni], acc[mi][ni], 0, 0, 0);
    }
#pragma unroll
    for (int mi = 0; mi < 2; ++mi)
#pragma unroll
      for (int ni = 0; ni < 2; ++ni)
#pragma unroll
        for (int q = 0; q < 4; ++q) {
          int m  = m0 + (mt0 + mi) * 16 + kslot * 4 + q;
          int nl = (nt0 + ni) * 16 + lane15;
          int b = m >> 10, t = m & 1023;              // m = b*T + t
          float v = acc[mi][ni][q] + bp[nl];
          if (isgate) v = 1.0f / (1.0f + expf(-v));
          proj[((size_t)t * BB + b) * 1536 + n0 + nl] = f2bf(v);
        }
  }
}

// =====================================================================
// Phase 2: recurrence, 2 interleaved chains. 32 blocks = 4 groups (g) x
// 8 col-slices (j). Block: chain A rows 32g..+15, chain B rows 32g+16..+31,
// cols j*64..+63. Per iteration: P1 computeA+store+flag; P2 pollB+loadB;
// P3 computeB+store+flag; P4 pollA+loadA — each chain's exchange latency
// hides under the other chain's compute. Operand-swapped MFMA puts 4
// consecutive state cols per lane -> register-direct packed coherent stores.
// =====================================================================
__global__ __launch_bounds__(256, 1) void recur_kernel(
    const float* __restrict__ s0,
    const float* __restrict__ A0w, const float* __restrict__ A1w,
    const unsigned short* __restrict__ proj,
    const float* __restrict__ alpha_p, const int* __restrict__ z_p,
    unsigned short* state_bf,          // [2][128][512] bf16 ping-pong
    unsigned int* flags,               // [2 chains][4 g][8 j]
    float* __restrict__ out)           // [128][1025][512]
{
  __shared__ unsigned short SsA[16 * 520];
  __shared__ unsigned short SsB[16 * 520];

  int tid = threadIdx.x, lane = tid & 63, wid = tid >> 6;   // 4 waves
  int g = blockIdx.x & 3, j = blockIdx.x >> 2;
  int bA = g * 32, bB = g * 32 + 16;
  int c0 = j * 64;
  int lane15 = lane & 15, kslot = lane >> 4;
  int colw = c0 + wid * 16 + lane15;          // A-frag col (M-operand)
  int ccb  = c0 + wid * 16 + kslot * 4;       // this lane's 4 output cols
  int rowA = bA + lane15, rowB = bB + lane15; // this lane's batch rows
  float alpha = *alpha_p; int z = *z_p; float om_a = 1.0f - alpha;

  // ---- A0/A1 fragments, register-resident (shared by both chains) ----
  bf16x8 Af0[16], Af1[16];
#pragma unroll
  for (int kk = 0; kk < 16; ++kk) {
    int k0 = kk * 32 + kslot * 8;
    Af0[kk] = pack8(A0w + (size_t)colw * SS + k0);
    Af1[kk] = pack8(A1w + (size_t)colw * SS + k0);
  }

  // ---- LDS state tiles from s0 ----
#pragma unroll
  for (int c2 = 0; c2 < 4; ++c2) {
    int e = tid + 256 * c2; int rr = e >> 6, kc = e & 63;
    *(bf16x8*)&SsA[rr * 520 + kc * 8] = pack8(s0 + (size_t)(bA + rr) * SS + kc * 8);
    *(bf16x8*)&SsB[rr * 520 + kc * 8] = pack8(s0 + (size_t)(bB + rr) * SS + kc * 8);
  }
  // ---- out[:,0,:] for this group's 32 rows (j==0 blocks) ----
  if (j == 0) {
#pragma unroll
    for (int it = 0; it < 16; ++it) {
      int task = tid + 256 * it;             // 32 rows x 128 float4
      int rr = task >> 7, f4 = task & 127;
      *(float4*)(out + (size_t)(bA + rr) * OUT_BSTRIDE + f4 * 4) =
          *(const float4*)(s0 + (size_t)(bA + rr) * SS + f4 * 4);
    }
  }
  // ---- fp32 carries ----
  float4 spA4 = *(const float4*)(s0 + (size_t)rowA * SS + ccb);
  float4 spB4 = *(const float4*)(s0 + (size_t)rowB * SS + ccb);
  float sprevA[4] = {spA4.x, spA4.y, spA4.z, spA4.w};
  float sprevB[4] = {spB4.x, spB4.y, spB4.z, spB4.w};

  // ---- proj pointers + t=0 prefetch ----
  const unsigned short* ppA = proj + (size_t)rowA * 1536 + ccb;
  const unsigned short* ppB = proj + (size_t)rowB * 1536 + ccb;
  u32x2 pA0 = *(const u32x2*)(ppA);
  u32x2 pA1 = *(const u32x2*)(ppA + 512);
  u32x2 pAg = *(const u32x2*)(ppA + 1024);
  u32x2 pB0 = *(const u32x2*)(ppB);
  u32x2 pB1 = *(const u32x2*)(ppB + 512);
  u32x2 pBg = *(const u32x2*)(ppB + 1024);

  unsigned int* flagA = flags + g * 8;
  unsigned int* flagB = flags + 32 + g * 8;

  __syncthreads();

  for (int t = 0; t < TT; ++t) {
    unsigned short* snext = state_bf + (size_t)((t + 1) & 1) * BB * SS;

    // ================= P1: chain A compute + publish =================
    {
      f32x4 a0e = {}, a0o = {}, a1e = {}, a1o = {};
      const unsigned short* sb = &SsA[lane15 * 520 + kslot * 8];
#pragma unroll
      for (int kk = 0; kk < 16; kk += 2) {
        bf16x8 f0 = *(const bf16x8*)(sb + kk * 32);
        bf16x8 f1 = *(const bf16x8*)(sb + (kk + 1) * 32);
        a0e = __builtin_amdgcn_mfma_f32_16x16x32_bf16(Af0[kk],     f0, a0e, 0, 0, 0);
        a1e = __builtin_amdgcn_mfma_f32_16x16x32_bf16(Af1[kk],     f0, a1e, 0, 0, 0);
        a0o = __builtin_amdgcn_mfma_f32_16x16x32_bf16(Af0[kk + 1], f1, a0o, 0, 0, 0);
        a1o = __builtin_amdgcn_mfma_f32_16x16x32_bf16(Af1[kk + 1], f1, a1o, 0, 0, 0);
      }
      float snA[4];
#pragma unroll
      for (int q = 0; q < 4; ++q) {
        float f0 = fast_tanh((a0e[q] + a0o[q]) + bfat(pA0, q));
        float f;
        if (z != 0) {
          float f1 = fast_tanh((a1e[q] + a1o[q]) + bfat(pA1, q));
          f = om_a * f0 + alpha * f1;
        } else f = f0;
        float gg = bfat(pAg, q);
        snA[q] = gg * f + (1.0f - gg) * sprevA[q];
        sprevA[q] = snA[q];
      }
      float4 o4 = {snA[0], snA[1], snA[2], snA[3]};
      *(float4*)(out + (size_t)rowA * OUT_BSTRIDE + (size_t)(t + 1) * SS + ccb) = o4;
      i32x2 w;
      w[0] = (int)(((unsigned)f2bf(snA[0])) | (((unsigned)f2bf(snA[1])) << 16));
      w[1] = (int)(((unsigned)f2bf(snA[2])) | (((unsigned)f2bf(snA[3])) << 16));
      st_coh_b64(snext + (size_t)rowA * SS + ccb, w);
      waitcnt_vm0();
      __syncthreads();
      if (tid == 0) st_coh_b32(flagA + j, (unsigned int)(t + 1));
      if (t + 1 < TT) {
        ppA += (size_t)BB * 1536;
        pA0 = *(const u32x2*)(ppA);
        pA1 = *(const u32x2*)(ppA + 512);
        pAg = *(const u32x2*)(ppA + 1024);
      }
    }

    // ================= P2: acquire chain B state t =================
    if (t > 0) {
      if (tid < 8) { while (ld_coh_b32(flagB + tid) < (unsigned int)t) {} }
      __syncthreads();
      const unsigned short* sbg = state_bf + (size_t)(t & 1) * BB * SS + (size_t)bB * SS;
      i32x4 v[4];
#pragma unroll
      for (int c2 = 0; c2 < 4; ++c2) {
        int e = tid + 256 * c2; int rr = e >> 6, kc = e & 63;
        v[c2] = ld_coh_b128_issue(sbg + rr * SS + kc * 8);
      }
      waitcnt_vm0();
#pragma unroll
      for (int c2 = 0; c2 < 4; ++c2) {
        int e = tid + 256 * c2; int rr = e >> 6, kc = e & 63;
        *(bf16x8*)&SsB[rr * 520 + kc * 8] = *(bf16x8*)&v[c2];
      }
      __syncthreads();
    }

    // ================= P3: chain B compute + publish =================
    {
      f32x4 a0e = {}, a0o = {}, a1e = {}, a1o = {};
      const unsigned short* sb = &SsB[lane15 * 520 + kslot * 8];
#pragma unroll
      for (int kk = 0; kk < 16; kk += 2) {
        bf16x8 f0 = *(const bf16x8*)(sb + kk * 32);
        bf16x8 f1 = *(const bf16x8*)(sb + (kk + 1) * 32);
        a0e = __builtin_amdgcn_mfma_f32_16x16x32_bf16(Af0[kk],     f0, a0e, 0, 0, 0);
        a1e = __builtin_amdgcn_mfma_f32_16x16x32_bf16(Af1[kk],     f0, a1e, 0, 0, 0);
        a0o = __builtin_amdgcn_mfma_f32_16x16x32_bf16(Af0[kk + 1], f1, a0o, 0, 0, 0);
        a1o = __builtin_amdgcn_mfma_f32_16x16x32_bf16(Af1[kk + 1], f1, a1o, 0, 0, 0);
      }
      float snB[4];
#pragma unroll
      for (int q = 0; q < 4; ++q) {
        float f0 = fast_tanh((a0e[q] + a0o[q]) + bfat(pB0, q));
        float f;
        if (z != 0) {
          float f1 = fast_tanh((a1e[q] + a1o[q]) + bfat(pB1, q));
          f = om_a * f0 + alpha * f1;
        } else f = f0;
        float gg = bfat(pBg, q);
        snB[q] = gg * f + (1.0f - gg) * sprevB[q];
        sprevB[q] = snB[q];
      }
      float4 o4 = {snB[0], snB[1], snB[2], snB[3]};
      *(float4*)(out + (size_t)rowB * OUT_BSTRIDE + (size_t)(t + 1) * SS + ccb) = o4;
      i32x2 w;
      w[0] = (int)(((unsigned)f2bf(snB[0])) | (((unsigned)f2bf(snB[1])) << 16));
      w[1] = (int)(((unsigned)f2bf(snB[2])) | (((unsigned)f2bf(snB[3])) << 16));
      st_coh_b64(snext + (size_t)rowB * SS + ccb, w);
      waitcnt_vm0();
      __syncthreads();
      if (tid == 0) st_coh_b32(flagB + j, (unsigned int)(t + 1));
      if (t + 1 < TT) {
        ppB += (size_t)BB * 1536;
        pB0 = *(const u32x2*)(ppB);
        pB1 = *(const u32x2*)(ppB + 512);
        pBg = *(const u32x2*)(ppB + 1024);
      }
    }

    // ================= P4: acquire chain A state t+1 =================
    if (t + 1 < TT) {
      if (tid < 8) { while (ld_coh_b32(flagA + tid) < (unsigned int)(t + 1)) {} }
      __syncthreads();
      const unsigned short* sbg = state_bf + (size_t)((t + 1) & 1) * BB * SS + (size_t)bA * SS;
      i32x4 v[4];
#pragma unroll
      for (int c2 = 0; c2 < 4; ++c2) {
        int e = tid + 256 * c2; int rr = e >> 6, kc = e & 63;
        v[c2] = ld_coh_b128_issue(sbg + rr * SS + kc * 8);
      }
      waitcnt_vm0();
#pragma unroll
      for (int c2 = 0; c2 < 4; ++c2) {
        int e = tid + 256 * c2; int rr = e >> 6, kc = e & 63;
        *(bf16x8*)&SsA[rr * 520 + kc * 8] = *(bf16x8*)&v[c2];
      }
      __syncthreads();
    }
  }
}

// =====================================================================
extern "C" void kernel_launch(void* const* d_in, const int* in_sizes, int n_in,
                              void* d_out, int out_size, void* d_ws, size_t ws_size,
                              hipStream_t stream) {
  const float* x   = (const float*)d_in[0];
  const float* s0  = (const float*)d_in[1];
  const float* A0w = (const float*)d_in[2];
  const float* B0w = (const float*)d_in[3];
  const float* B0b = (const float*)d_in[4];
  const float* A1w = (const float*)d_in[5];
  const float* B1w = (const float*)d_in[6];
  const float* B1b = (const float*)d_in[7];
  const float* Gw  = (const float*)d_in[8];
  const float* Gb  = (const float*)d_in[9];
  const float* alp = (const float*)d_in[10];
  const int*   zp  = (const int*)d_in[11];
  float* out = (float*)d_out;

  char* ws = (char*)d_ws;
  size_t proj_bytes  = (size_t)BB * TT * 1536 * 2;        // 402,653,184
  size_t state_off   = proj_bytes;
  size_t state_bytes = (size_t)2 * BB * SS * 2;           // 262,144
  size_t flag_off    = state_off + state_bytes;
  unsigned short* proj     = (unsigned short*)(ws);
  unsigned short* state_bf = (unsigned short*)(ws + state_off);
  unsigned int*   flags    = (unsigned int*)(ws + flag_off);

  hipMemsetAsync(flags, 0, 64 * sizeof(unsigned int), stream);

  proj_kernel<<<dim3(131072 / 64), dim3(256), 0, stream>>>(
      x, B0w, B0b, B1w, B1b, Gw, Gb, proj);

  recur_kernel<<<dim3(32), dim3(256), 0, stream>>>(
      s0, A0w, A1w, proj, alp, zp, state_bf, flags, out);
}